// Round 1
// baseline (546.111 us; speedup 1.0000x reference)
//
#include <hip/hip_runtime.h>

// ---------- types ----------
typedef __attribute__((ext_vector_type(8))) short bf16x8;   // 8 bf16 in 4 VGPRs
typedef __attribute__((ext_vector_type(4))) float f32x4;    // MFMA accumulator

__device__ inline f32x4 mfma16(bf16x8 a, bf16x8 b, f32x4 c) {
    return __builtin_amdgcn_mfma_f32_16x16x32_bf16(a, b, c, 0, 0, 0);
}

__device__ inline short f2bf(float f) {
    unsigned u = __builtin_bit_cast(unsigned, f);
    unsigned r = (u + 0x7fffu + ((u >> 16) & 1u)) >> 16;   // RNE
    return (short)r;
}
__device__ inline float bf2f(short h) {
    unsigned u = ((unsigned)(unsigned short)h) << 16;
    return __builtin_bit_cast(float, u);
}

// ---------- constants ----------
#define T_SEQ 4096
#define C_DIM 1024
#define N_HEAD 16
#define HEAD_DIM 64

// ---------- kernel 1: cast fp32 -> bf16 for x + 4 weights ----------
__global__ __launch_bounds__(256) void cast5(
    const float* __restrict__ s0, const float* __restrict__ s1,
    const float* __restrict__ s2, const float* __restrict__ s3,
    const float* __restrict__ s4,
    short* __restrict__ d0, short* __restrict__ d1, short* __restrict__ d2,
    short* __restrict__ d3, short* __restrict__ d4,
    int n0, int n1, int n2, int n3, int n4)
{
    int z = blockIdx.y;
    const float* s; short* d; int n;
    switch (z) {
        case 0: s = s0; d = d0; n = n0; break;
        case 1: s = s1; d = d1; n = n1; break;
        case 2: s = s2; d = d2; n = n2; break;
        case 3: s = s3; d = d3; n = n3; break;
        default: s = s4; d = d4; n = n4; break;
    }
    int i = (blockIdx.x * 256 + threadIdx.x) * 4;
    if (i >= n) return;
    float4 v = *(const float4*)&s[i];
    short4 o;
    o.x = f2bf(v.x); o.y = f2bf(v.y); o.z = f2bf(v.z); o.w = f2bf(v.w);
    *(short4*)&d[i] = o;
}

// ---------- kernel 2: NT GEMM  C[m][n] = sum_k A[m][k] * B[n][k] ----------
// 128x128 tile, 4 waves (2x2), 4x4 fragments of 16x16x32 per wave, BK=32.
// blockIdx.z selects among up to 3 (B, C) pairs (fused QKV).
template<int OBF>
__global__ __launch_bounds__(256) void gemm3(
    const short* __restrict__ A,
    const short* __restrict__ B0, const short* __restrict__ B1,
    const short* __restrict__ B2,
    void* C0, void* C1, void* C2,
    int M, int N, int K)
{
    const short* B = (blockIdx.z == 0) ? B0 : ((blockIdx.z == 1) ? B1 : B2);
    void*        C = (blockIdx.z == 0) ? C0 : ((blockIdx.z == 1) ? C1 : C2);

    __shared__ alignas(16) short sA[128 * 32];
    __shared__ alignas(16) short sB[128 * 32];

    int tid  = threadIdx.x;
    int wave = tid >> 6, lane = tid & 63;
    int lhi  = lane >> 4, llo = lane & 15;
    int wr   = wave >> 1, wc = wave & 1;
    int row0 = blockIdx.x * 128, col0 = blockIdx.y * 128;

    f32x4 acc[4][4];
#pragma unroll
    for (int m = 0; m < 4; m++)
#pragma unroll
        for (int n = 0; n < 4; n++)
            acc[m][n] = (f32x4){0.f, 0.f, 0.f, 0.f};

    for (int k0 = 0; k0 < K; k0 += 32) {
        __syncthreads();   // protect LDS from previous iteration's readers
#pragma unroll
        for (int i = 0; i < 2; i++) {
            int idx = i * 256 + tid;            // 0..511  -> 128 rows x 4 chunks
            int r = idx >> 2, cs = (idx & 3) * 8;
            *(int4*)&sA[r * 32 + cs] = *(const int4*)&A[(size_t)(row0 + r) * K + k0 + cs];
            *(int4*)&sB[r * 32 + cs] = *(const int4*)&B[(size_t)(col0 + r) * K + k0 + cs];
        }
        __syncthreads();

        bf16x8 af[4], bfv[4];
#pragma unroll
        for (int m = 0; m < 4; m++)
            af[m] = *(const bf16x8*)&sA[(wr * 64 + m * 16 + llo) * 32 + lhi * 8];
#pragma unroll
        for (int n = 0; n < 4; n++)
            bfv[n] = *(const bf16x8*)&sB[(wc * 64 + n * 16 + llo) * 32 + lhi * 8];
#pragma unroll
        for (int m = 0; m < 4; m++)
#pragma unroll
            for (int n = 0; n < 4; n++)
                acc[m][n] = mfma16(af[m], bfv[n], acc[m][n]);
    }

#pragma unroll
    for (int m = 0; m < 4; m++)
#pragma unroll
        for (int n = 0; n < 4; n++)
#pragma unroll
            for (int r = 0; r < 4; r++) {
                int row = row0 + wr * 64 + m * 16 + lhi * 4 + r;
                int col = col0 + wc * 64 + n * 16 + llo;
                float v = acc[m][n][r];
                if (OBF) ((short*)C)[(size_t)row * N + col] = f2bf(v);
                else     ((float*)C)[(size_t)row * N + col] = v;
            }
}

// ---------- kernel 3: RoPE + RMSNorm, [T][C] bf16 -> per-head [H][T][D] bf16 ----------
// One wave per (t, h) row of 64. outscale folds 1/sqrt(D) for q.
__global__ __launch_bounds__(256) void rope_rms(
    const short* __restrict__ Qb, const float* __restrict__ cosT,
    const float* __restrict__ sinT, short* __restrict__ qn, float outscale)
{
    int idx = blockIdx.x * 4 + (threadIdx.x >> 6);   // (t*16 + h)
    int t = idx >> 4, h = idx & 15;
    int d = threadIdx.x & 63;

    float v = bf2f(Qb[t * C_DIM + h * HEAD_DIM + d]);
    int d2 = d & 31;
    float c = cosT[t * 32 + d2], s = sinT[t * 32 + d2];
    float other = __shfl_xor(v, 32);                  // partner element (d +/- 32)
    // ref: out1 = x1*c + x2*s ; out2 = -x1*s + x2*c
    float r = (d < 32) ? (v * c + other * s) : (v * c - other * s);

    float sq = r * r;
#pragma unroll
    for (int off = 32; off >= 1; off >>= 1) sq += __shfl_xor(sq, off);
    float inv = rsqrtf(sq * (1.0f / 64.0f) + 1e-6f);

    qn[((size_t)h * T_SEQ + t) * HEAD_DIM + d] = f2bf(r * inv * outscale);
}

// ---------- kernel 4: V transpose [T][C] -> [H][D][T] bf16, scaled by 1/(sqrt(T)+1e-6) ----------
__global__ __launch_bounds__(256) void vtrans(
    const short* __restrict__ Vb, short* __restrict__ vt)
{
    __shared__ short sT[64 * 65];
    int h = blockIdx.y, tb = blockIdx.x;
    int tid = threadIdx.x;
    const float inv64 = 1.0f / (64.0f + 1e-6f);
#pragma unroll
    for (int i = 0; i < 16; i++) {
        int linear = i * 256 + tid;
        int r = linear >> 6, c = linear & 63;        // r: t within tile, c: d
        float v = bf2f(Vb[(size_t)(tb * 64 + r) * C_DIM + h * HEAD_DIM + c]) * inv64;
        sT[c * 65 + r] = f2bf(v);
    }
    __syncthreads();
#pragma unroll
    for (int i = 0; i < 16; i++) {
        int linear = i * 256 + tid;
        int dd = linear >> 6, tt = linear & 63;
        vt[((size_t)(h * HEAD_DIM + dd)) * T_SEQ + tb * 64 + tt] = sT[dd * 65 + tt];
    }
}

// ---------- kernel 5: causal sigmoid attention ----------
// qn,kn: [H][T][D] bf16 (q pre-scaled by 1/8). vt: [H][D][T] bf16 (pre-scaled by 1/(sqrt(T)+1e-6)).
// Block: 64 q-rows, 4 waves, each wave owns 16 rows. K-tiles of 128.
// No barriers: each wave's P slab in LDS is private to the wave.
__global__ __launch_bounds__(256) void attn_kern(
    const short* __restrict__ qn, const short* __restrict__ kn,
    const short* __restrict__ vt, short* __restrict__ yb)
{
    int h = blockIdx.y, bq = blockIdx.x;
    int tid = threadIdx.x, wave = tid >> 6, lane = tid & 63;
    int lhi = lane >> 4, llo = lane & 15;
    const short* Qh = qn + (size_t)h * T_SEQ * HEAD_DIM;
    const short* Kh = kn + (size_t)h * T_SEQ * HEAD_DIM;
    const short* Vh = vt + (size_t)h * HEAD_DIM * T_SEQ;
    int qbase = bq * 64;

    __shared__ alignas(16) short P[64 * 128];   // [q-row-in-block][j-in-ktile]

    bf16x8 qf[2];
#pragma unroll
    for (int dk = 0; dk < 2; dk++)
        qf[dk] = *(const bf16x8*)&Qh[(size_t)(qbase + wave * 16 + llo) * HEAD_DIM + dk * 32 + lhi * 8];

    f32x4 yacc[4];
#pragma unroll
    for (int n = 0; n < 4; n++) yacc[n] = (f32x4){0.f, 0.f, 0.f, 0.f};

    int nkt = bq / 2 + 1;   // number of 128-wide k-tiles needed (causal)
    for (int kt = 0; kt < nkt; kt++) {
        int kb = kt * 128;
        // ---- S = Q K^T (scaled), mask, sigmoid -> P (bf16, per-wave LDS slab) ----
#pragma unroll
        for (int n = 0; n < 8; n++) {
            f32x4 s = (f32x4){0.f, 0.f, 0.f, 0.f};
#pragma unroll
            for (int dk = 0; dk < 2; dk++) {
                bf16x8 kf = *(const bf16x8*)&Kh[(size_t)(kb + n * 16 + llo) * HEAD_DIM + dk * 32 + lhi * 8];
                s = mfma16(qf[dk], kf, s);
            }
#pragma unroll
            for (int r = 0; r < 4; r++) {
                int i = qbase + wave * 16 + lhi * 4 + r;
                int j = kb + n * 16 + llo;
                float sv = s[r];
                float p = (j <= i) ? (1.0f / (1.0f + __expf(-sv))) : 0.0f;
                P[(wave * 16 + lhi * 4 + r) * 128 + n * 16 + llo] = f2bf(p);
            }
        }
        // ---- y += P V ----
#pragma unroll
        for (int ks = 0; ks < 4; ks++) {
            bf16x8 pf = *(const bf16x8*)&P[(wave * 16 + llo) * 128 + ks * 32 + lhi * 8];
#pragma unroll
            for (int n = 0; n < 4; n++) {
                bf16x8 vf = *(const bf16x8*)&Vh[(size_t)(n * 16 + llo) * T_SEQ + kb + ks * 32 + lhi * 8];
                yacc[n] = mfma16(pf, vf, yacc[n]);
            }
        }
    }

    // epilogue: yb[t][h*64 + d] bf16
#pragma unroll
    for (int n = 0; n < 4; n++)
#pragma unroll
        for (int r = 0; r < 4; r++)
            yb[(size_t)(qbase + wave * 16 + lhi * 4 + r) * C_DIM + h * HEAD_DIM + n * 16 + llo]
                = f2bf(yacc[n][r]);
}

// ---------- launch ----------
extern "C" void kernel_launch(void* const* d_in, const int* in_sizes, int n_in,
                              void* d_out, int out_size, void* d_ws, size_t ws_size,
                              hipStream_t stream)
{
    const float* x    = (const float*)d_in[0];
    const float* cosT = (const float*)d_in[1];
    const float* sinT = (const float*)d_in[2];
    const float* wq   = (const float*)d_in[3];
    const float* wk   = (const float*)d_in[4];
    const float* wv   = (const float*)d_in[5];
    const float* wp   = (const float*)d_in[6];

    char* ws = (char*)d_ws;
    const size_t MB = 1024 * 1024;
    short* xb  = (short*)(ws + 0);        // [4096][1024] bf16   8 MiB
    short* wqb = (short*)(ws + 8  * MB);  // [1024][1024] bf16   2 MiB
    short* wkb = (short*)(ws + 10 * MB);
    short* wvb = (short*)(ws + 12 * MB);
    short* wpb = (short*)(ws + 14 * MB);
    short* Qb  = (short*)(ws + 16 * MB);  // [4096][1024] bf16   8 MiB
    short* Kb  = (short*)(ws + 24 * MB);
    short* Vb  = (short*)(ws + 32 * MB);
    short* qnb = (short*)(ws + 40 * MB);  // [16][4096][64] bf16 8 MiB
    short* knb = (short*)(ws + 48 * MB);
    short* vtb = (short*)(ws + 56 * MB);  // [16][64][4096] bf16 8 MiB
    short* yb  = (short*)(ws + 64 * MB);  // [4096][1024] bf16   8 MiB

    // 1. cast inputs to bf16
    cast5<<<dim3(4096, 5, 1), 256, 0, stream>>>(
        x, wq, wk, wv, wp, xb, wqb, wkb, wvb, wpb,
        T_SEQ * C_DIM, C_DIM * C_DIM, C_DIM * C_DIM, C_DIM * C_DIM, C_DIM * C_DIM);

    // 2. fused QKV GEMM (bf16 out)
    gemm3<1><<<dim3(32, 8, 3), 256, 0, stream>>>(
        xb, wqb, wkb, wvb, (void*)Qb, (void*)Kb, (void*)Vb, T_SEQ, C_DIM, C_DIM);

    // 3. RoPE + RMSNorm (q gets 1/sqrt(D) folded in)
    rope_rms<<<16384, 256, 0, stream>>>(Qb, cosT, sinT, qnb, 0.125f);
    rope_rms<<<16384, 256, 0, stream>>>(Kb, cosT, sinT, knb, 1.0f);

    // 4. V transpose + 1/(sqrt(T)+1e-6)
    vtrans<<<dim3(64, 16, 1), 256, 0, stream>>>(Vb, vtb);

    // 5. causal sigmoid attention
    attn_kern<<<dim3(64, 16, 1), 256, 0, stream>>>(qnb, knb, vtb, yb);

    // 6. output projection (fp32 out)
    gemm3<0><<<dim3(32, 8, 1), 256, 0, stream>>>(
        yb, wpb, wpb, wpb, d_out, d_out, d_out, T_SEQ, C_DIM, C_DIM);
}

// Round 2
// 228.259 us; speedup vs baseline: 2.3925x; 2.3925x over previous
//
#include <hip/hip_runtime.h>

// ---------- types ----------
typedef __attribute__((ext_vector_type(8))) short bf16x8;   // 8 bf16 in 4 VGPRs
typedef __attribute__((ext_vector_type(4))) float f32x4;    // MFMA accumulator 16x16
typedef __attribute__((ext_vector_type(16))) float f32x16;  // MFMA accumulator 32x32

__device__ inline f32x4 mfma16(bf16x8 a, bf16x8 b, f32x4 c) {
    return __builtin_amdgcn_mfma_f32_16x16x32_bf16(a, b, c, 0, 0, 0);
}
__device__ inline f32x16 mfma32(bf16x8 a, bf16x8 b, f32x16 c) {
    return __builtin_amdgcn_mfma_f32_32x32x16_bf16(a, b, c, 0, 0, 0);
}

__device__ inline short f2bf(float f) {
    unsigned u = __builtin_bit_cast(unsigned, f);
    unsigned r = (u + 0x7fffu + ((u >> 16) & 1u)) >> 16;   // RNE
    return (short)r;
}
__device__ inline float bf2f(short h) {
    unsigned u = ((unsigned)(unsigned short)h) << 16;
    return __builtin_bit_cast(float, u);
}

// ---------- constants ----------
#define T_SEQ 4096
#define C_DIM 1024
#define N_HEAD 16
#define HEAD_DIM 64

// ---------- kernel 1: cast fp32 -> bf16 for x + 4 weights ----------
__global__ __launch_bounds__(256) void cast5(
    const float* __restrict__ s0, const float* __restrict__ s1,
    const float* __restrict__ s2, const float* __restrict__ s3,
    const float* __restrict__ s4,
    short* __restrict__ d0, short* __restrict__ d1, short* __restrict__ d2,
    short* __restrict__ d3, short* __restrict__ d4,
    int n0, int n1, int n2, int n3, int n4)
{
    int z = blockIdx.y;
    const float* s; short* d; int n;
    switch (z) {
        case 0: s = s0; d = d0; n = n0; break;
        case 1: s = s1; d = d1; n = n1; break;
        case 2: s = s2; d = d2; n = n2; break;
        case 3: s = s3; d = d3; n = n3; break;
        default: s = s4; d = d4; n = n4; break;
    }
    int i = (blockIdx.x * 256 + threadIdx.x) * 4;
    if (i >= n) return;
    float4 v = *(const float4*)&s[i];
    short4 o;
    o.x = f2bf(v.x); o.y = f2bf(v.y); o.z = f2bf(v.z); o.w = f2bf(v.w);
    *(short4*)&d[i] = o;
}

// ---------- kernel 2: NT GEMM  C[m][n] = sum_k A[m][k] * B[n][k] ----------
template<int OBF>
__global__ __launch_bounds__(256) void gemm3(
    const short* __restrict__ A,
    const short* __restrict__ B0, const short* __restrict__ B1,
    const short* __restrict__ B2,
    void* C0, void* C1, void* C2,
    int M, int N, int K)
{
    const short* B = (blockIdx.z == 0) ? B0 : ((blockIdx.z == 1) ? B1 : B2);
    void*        C = (blockIdx.z == 0) ? C0 : ((blockIdx.z == 1) ? C1 : C2);

    __shared__ alignas(16) short sA[128 * 32];
    __shared__ alignas(16) short sB[128 * 32];

    int tid  = threadIdx.x;
    int wave = tid >> 6, lane = tid & 63;
    int lhi  = lane >> 4, llo = lane & 15;
    int wr   = wave >> 1, wc = wave & 1;
    int row0 = blockIdx.x * 128, col0 = blockIdx.y * 128;

    f32x4 acc[4][4];
#pragma unroll
    for (int m = 0; m < 4; m++)
#pragma unroll
        for (int n = 0; n < 4; n++)
            acc[m][n] = (f32x4){0.f, 0.f, 0.f, 0.f};

    for (int k0 = 0; k0 < K; k0 += 32) {
        __syncthreads();
#pragma unroll
        for (int i = 0; i < 2; i++) {
            int idx = i * 256 + tid;
            int r = idx >> 2, cs = (idx & 3) * 8;
            *(int4*)&sA[r * 32 + cs] = *(const int4*)&A[(size_t)(row0 + r) * K + k0 + cs];
            *(int4*)&sB[r * 32 + cs] = *(const int4*)&B[(size_t)(col0 + r) * K + k0 + cs];
        }
        __syncthreads();

        bf16x8 af[4], bfv[4];
#pragma unroll
        for (int m = 0; m < 4; m++)
            af[m] = *(const bf16x8*)&sA[(wr * 64 + m * 16 + llo) * 32 + lhi * 8];
#pragma unroll
        for (int n = 0; n < 4; n++)
            bfv[n] = *(const bf16x8*)&sB[(wc * 64 + n * 16 + llo) * 32 + lhi * 8];
#pragma unroll
        for (int m = 0; m < 4; m++)
#pragma unroll
            for (int n = 0; n < 4; n++)
                acc[m][n] = mfma16(af[m], bfv[n], acc[m][n]);
    }

#pragma unroll
    for (int m = 0; m < 4; m++)
#pragma unroll
        for (int n = 0; n < 4; n++)
#pragma unroll
            for (int r = 0; r < 4; r++) {
                int row = row0 + wr * 64 + m * 16 + lhi * 4 + r;
                int col = col0 + wc * 64 + n * 16 + llo;
                float v = acc[m][n][r];
                if (OBF) ((short*)C)[(size_t)row * N + col] = f2bf(v);
                else     ((float*)C)[(size_t)row * N + col] = v;
            }
}

// ---------- kernel 3: RoPE + RMSNorm, [T][C] bf16 -> per-head [H][T][D] bf16 ----------
__global__ __launch_bounds__(256) void rope_rms(
    const short* __restrict__ Qb, const float* __restrict__ cosT,
    const float* __restrict__ sinT, short* __restrict__ qn, float outscale)
{
    int idx = blockIdx.x * 4 + (threadIdx.x >> 6);   // (t*16 + h)
    int t = idx >> 4, h = idx & 15;
    int d = threadIdx.x & 63;

    float v = bf2f(Qb[t * C_DIM + h * HEAD_DIM + d]);
    int d2 = d & 31;
    float c = cosT[t * 32 + d2], s = sinT[t * 32 + d2];
    float other = __shfl_xor(v, 32);
    float r = (d < 32) ? (v * c + other * s) : (v * c - other * s);

    float sq = r * r;
#pragma unroll
    for (int off = 32; off >= 1; off >>= 1) sq += __shfl_xor(sq, off);
    float inv = rsqrtf(sq * (1.0f / 64.0f) + 1e-6f);

    qn[((size_t)h * T_SEQ + t) * HEAD_DIM + d] = f2bf(r * inv * outscale);
}

// ---------- kernel 4: V transpose [T][C] -> [H][D][T] bf16, scaled ----------
__global__ __launch_bounds__(256) void vtrans(
    const short* __restrict__ Vb, short* __restrict__ vt)
{
    __shared__ short sT[64 * 65];
    int h = blockIdx.y, tb = blockIdx.x;
    int tid = threadIdx.x;
    const float inv64 = 1.0f / (64.0f + 1e-6f);
#pragma unroll
    for (int i = 0; i < 16; i++) {
        int linear = i * 256 + tid;
        int r = linear >> 6, c = linear & 63;
        float v = bf2f(Vb[(size_t)(tb * 64 + r) * C_DIM + h * HEAD_DIM + c]) * inv64;
        sT[c * 65 + r] = f2bf(v);
    }
    __syncthreads();
#pragma unroll
    for (int i = 0; i < 16; i++) {
        int linear = i * 256 + tid;
        int dd = linear >> 6, tt = linear & 63;
        vt[((size_t)(h * HEAD_DIM + dd)) * T_SEQ + tb * 64 + tt] = sT[dd * 65 + tt];
    }
}

// ---------- kernel 5: causal sigmoid attention, 32x32 MFMA, swapped QK^T ----------
// qn,kn: [H][T][D] bf16 (q pre-scaled 1/8). vt: [H][D][T] bf16 (pre-scaled 1/64.000001).
// Block: 512 thr = 8 waves = 4 q-bands (32 rows) x 2 kv-teams (64 kv each of a 128 tile).
// Block handles q-tiles (j, 31-j): uniform 33 k-tile steps. 256 blocks = 1/CU.
// P path: swapped QK^T (q = lane&31) -> sigmoid in regs -> wave-private XOR-swizzled
// LDS slab -> b128 A-frag reads for PV. No barriers in the k-loop.
__global__ __launch_bounds__(512) void attn2(
    const short* __restrict__ qn, const short* __restrict__ kn,
    const short* __restrict__ vt, short* __restrict__ yb)
{
    __shared__ alignas(16) char Smem[32768];   // 8 x 4KB P slabs; reused as Y reduce buf

    int id = blockIdx.x;
    int hp = id & 7, kk = id >> 3;             // head-pair -> XCD locality
    int h  = hp * 2 + (kk & 1);
    int jp = kk >> 1;                           // 0..15 -> q-tile pair (jp, 31-jp)

    int tid = threadIdx.x;
    int wave = tid >> 6, lane = tid & 63;
    int lo = lane & 31, hi = lane >> 5;
    int band = wave & 3, team = wave >> 2;

    const short* Qh = qn + (size_t)h * T_SEQ * HEAD_DIM;
    const short* Kh = kn + (size_t)h * T_SEQ * HEAD_DIM;
    const short* Vh = vt + (size_t)h * HEAD_DIM * T_SEQ;

    char* mp = Smem + wave * 4096;              // my P slab: [32 q][64 kv] bf16, row 128B
    float* Yred = (float*)Smem;                 // overlay: [4 band][32 q][64 d] f32
    unsigned swz  = (unsigned)((lo & 7) << 4);  // XOR swizzle on 16B-granule bits (4..6)
    unsigned prow = (unsigned)(lo * 128);

    for (int halfi = 0; halfi < 2; halfi++) {
        int t  = halfi ? (31 - jp) : jp;
        int q0 = t * 128;
        int qg = q0 + band * 32 + lo;           // this lane's q column

        bf16x8 qf[4];
#pragma unroll
        for (int dk = 0; dk < 4; dk++)
            qf[dk] = *(const bf16x8*)&Qh[(size_t)(q0 + band * 32 + lo) * HEAD_DIM + dk * 16 + hi * 8];

        f32x16 yac[2];
#pragma unroll
        for (int d = 0; d < 2; d++)
#pragma unroll
            for (int r = 0; r < 16; r++) yac[d][r] = 0.f;

        for (int kt = 0; kt <= t; kt++) {
            int kb = kt * 128 + team * 64;      // this team's 64-kv chunk
            bool diag = (kt == t);
#pragma unroll
            for (int f = 0; f < 2; f++) {
                // ---- S^T = K Q^T : C col = q (lane&31), row = kv (crow) ----
                f32x16 s;
#pragma unroll
                for (int r = 0; r < 16; r++) s[r] = 0.f;
#pragma unroll
                for (int dk = 0; dk < 4; dk++) {
                    bf16x8 kf = *(const bf16x8*)&Kh[(size_t)(kb + f * 32 + lo) * HEAD_DIM + dk * 16 + hi * 8];
                    s = mfma32(kf, qf[dk], s);
                }
                // ---- sigmoid (+ causal mask on diagonal tile), pack to bf16 ----
                unsigned pb[16];
                if (diag) {
#pragma unroll
                    for (int r = 0; r < 16; r++) {
                        int kvg = kb + f * 32 + (r & 3) + 8 * (r >> 2) + 4 * hi;
                        float pv = __builtin_amdgcn_rcpf(1.f + __expf(-s[r]));
                        pb[r] = (kvg <= qg) ? __builtin_bit_cast(unsigned, pv) : 0u;
                    }
                } else {
#pragma unroll
                    for (int r = 0; r < 16; r++) {
                        float pv = __builtin_amdgcn_rcpf(1.f + __expf(-s[r]));
                        pb[r] = __builtin_bit_cast(unsigned, pv);
                    }
                }
                // ---- write P (4 consecutive kv per b64), XOR-swizzled ----
#pragma unroll
                for (int sq = 0; sq < 4; sq++) {
                    unsigned w0 = __builtin_amdgcn_perm(pb[4 * sq + 1], pb[4 * sq + 0], 0x07060302u);
                    unsigned w1 = __builtin_amdgcn_perm(pb[4 * sq + 3], pb[4 * sq + 2], 0x07060302u);
                    unsigned off = prow + (((unsigned)(f * 64 + sq * 16)) ^ swz) + (unsigned)(hi * 8);
                    *(uint2*)(mp + off) = make_uint2(w0, w1);
                }
                // ---- PV over this f's two 16-kv chunks ----
#pragma unroll
                for (int kq = 0; kq < 2; kq++) {
                    int ks = f * 2 + kq;
                    unsigned roff = prow + (((unsigned)(ks * 32 + hi * 16)) ^ swz);
                    bf16x8 pa = *(const bf16x8*)(mp + roff);
#pragma unroll
                    for (int d = 0; d < 2; d++) {
                        bf16x8 vf = *(const bf16x8*)&Vh[(size_t)(d * 32 + lo) * T_SEQ + kb + ks * 16 + hi * 8];
                        yac[d] = mfma32(pa, vf, yac[d]);
                    }
                }
            }
        }

        // ---- cross-team reduce (kv halves) + store ----
        __syncthreads();                         // all P-slab reads done before overlay
        if (team == 1) {
#pragma unroll
            for (int d = 0; d < 2; d++)
#pragma unroll
                for (int r = 0; r < 16; r++) {
                    int crow = (r & 3) + 8 * (r >> 2) + 4 * hi;
                    Yred[((band * 32 + crow) * 64) + d * 32 + lo] = yac[d][r];
                }
        }
        __syncthreads();
        if (team == 0) {
#pragma unroll
            for (int d = 0; d < 2; d++)
#pragma unroll
                for (int r = 0; r < 16; r++) {
                    int crow = (r & 3) + 8 * (r >> 2) + 4 * hi;
                    float v = yac[d][r] + Yred[((band * 32 + crow) * 64) + d * 32 + lo];
                    yb[(size_t)(q0 + band * 32 + crow) * C_DIM + h * HEAD_DIM + d * 32 + lo] = f2bf(v);
                }
        }
        __syncthreads();
    }
}

// ---------- launch ----------
extern "C" void kernel_launch(void* const* d_in, const int* in_sizes, int n_in,
                              void* d_out, int out_size, void* d_ws, size_t ws_size,
                              hipStream_t stream)
{
    const float* x    = (const float*)d_in[0];
    const float* cosT = (const float*)d_in[1];
    const float* sinT = (const float*)d_in[2];
    const float* wq   = (const float*)d_in[3];
    const float* wk   = (const float*)d_in[4];
    const float* wv   = (const float*)d_in[5];
    const float* wp   = (const float*)d_in[6];

    char* ws = (char*)d_ws;
    const size_t MB = 1024 * 1024;
    short* xb  = (short*)(ws + 0);
    short* wqb = (short*)(ws + 8  * MB);
    short* wkb = (short*)(ws + 10 * MB);
    short* wvb = (short*)(ws + 12 * MB);
    short* wpb = (short*)(ws + 14 * MB);
    short* Qb  = (short*)(ws + 16 * MB);
    short* Kb  = (short*)(ws + 24 * MB);
    short* Vb  = (short*)(ws + 32 * MB);
    short* qnb = (short*)(ws + 40 * MB);
    short* knb = (short*)(ws + 48 * MB);
    short* vtb = (short*)(ws + 56 * MB);
    short* yb  = (short*)(ws + 64 * MB);

    cast5<<<dim3(4096, 5, 1), 256, 0, stream>>>(
        x, wq, wk, wv, wp, xb, wqb, wkb, wvb, wpb,
        T_SEQ * C_DIM, C_DIM * C_DIM, C_DIM * C_DIM, C_DIM * C_DIM, C_DIM * C_DIM);

    gemm3<1><<<dim3(32, 8, 3), 256, 0, stream>>>(
        xb, wqb, wkb, wvb, (void*)Qb, (void*)Kb, (void*)Vb, T_SEQ, C_DIM, C_DIM);

    rope_rms<<<16384, 256, 0, stream>>>(Qb, cosT, sinT, qnb, 0.125f);
    rope_rms<<<16384, 256, 0, stream>>>(Kb, cosT, sinT, knb, 1.0f);

    vtrans<<<dim3(64, 16, 1), 256, 0, stream>>>(Vb, vtb);

    attn2<<<256, 512, 0, stream>>>(qnb, knb, vtb, yb);

    gemm3<0><<<dim3(32, 8, 1), 256, 0, stream>>>(
        yb, wpb, wpb, wpb, d_out, d_out, d_out, T_SEQ, C_DIM, C_DIM);
}

// Round 3
// 218.771 us; speedup vs baseline: 2.4963x; 1.0434x over previous
//
#include <hip/hip_runtime.h>

// ---------- types ----------
typedef __attribute__((ext_vector_type(8))) short bf16x8;   // 8 bf16 in 4 VGPRs
typedef __attribute__((ext_vector_type(4))) float f32x4;    // MFMA accumulator 16x16
typedef __attribute__((ext_vector_type(16))) float f32x16;  // MFMA accumulator 32x32

__device__ inline f32x4 mfma16(bf16x8 a, bf16x8 b, f32x4 c) {
    return __builtin_amdgcn_mfma_f32_16x16x32_bf16(a, b, c, 0, 0, 0);
}
__device__ inline f32x16 mfma32(bf16x8 a, bf16x8 b, f32x16 c) {
    return __builtin_amdgcn_mfma_f32_32x32x16_bf16(a, b, c, 0, 0, 0);
}

__device__ inline short f2bf(float f) {
    unsigned u = __builtin_bit_cast(unsigned, f);
    unsigned r = (u + 0x7fffu + ((u >> 16) & 1u)) >> 16;   // RNE
    return (short)r;
}
__device__ inline float bf2f(short h) {
    unsigned u = ((unsigned)(unsigned short)h) << 16;
    return __builtin_bit_cast(float, u);
}

__device__ inline unsigned cvt_pk_bf16(float lo, float hi) {
    unsigned r;
    asm("v_cvt_pk_bf16_f32 %0, %1, %2" : "=v"(r) : "v"(lo), "v"(hi));
    return r;
}
__device__ inline void plane_swap(unsigned& a, unsigned& b) {
    asm("v_permlane32_swap_b32 %0, %1" : "+v"(a), "+v"(b));
}

#define GAS(p) (const __attribute__((address_space(1))) void*)(p)
#define LAS(p) (__attribute__((address_space(3))) void*)(p)

// ---------- constants ----------
#define T_SEQ 4096
#define C_DIM 1024
#define N_HEAD 16
#define HEAD_DIM 64

// ---------- kernel 1: cast fp32 -> bf16 for x + 4 weights ----------
__global__ __launch_bounds__(256) void cast5(
    const float* __restrict__ s0, const float* __restrict__ s1,
    const float* __restrict__ s2, const float* __restrict__ s3,
    const float* __restrict__ s4,
    short* __restrict__ d0, short* __restrict__ d1, short* __restrict__ d2,
    short* __restrict__ d3, short* __restrict__ d4,
    int n0, int n1, int n2, int n3, int n4)
{
    int z = blockIdx.y;
    const float* s; short* d; int n;
    switch (z) {
        case 0: s = s0; d = d0; n = n0; break;
        case 1: s = s1; d = d1; n = n1; break;
        case 2: s = s2; d = d2; n = n2; break;
        case 3: s = s3; d = d3; n = n3; break;
        default: s = s4; d = d4; n = n4; break;
    }
    int i = (blockIdx.x * 256 + threadIdx.x) * 4;
    if (i >= n) return;
    float4 v = *(const float4*)&s[i];
    short4 o;
    o.x = f2bf(v.x); o.y = f2bf(v.y); o.z = f2bf(v.z); o.w = f2bf(v.w);
    *(short4*)&d[i] = o;
}

// ---------- kernel 2: NT GEMM via global_load_lds (m97 structure) ----------
// C[m][n] = sum_k A[m][k] * B[n][k]; 128x128 tile, 4 waves, BK=32.
template<int OBF>
__global__ __launch_bounds__(256) void gemm3(
    const short* __restrict__ A,
    const short* __restrict__ B0, const short* __restrict__ B1,
    const short* __restrict__ B2,
    void* C0, void* C1, void* C2,
    int M, int N, int K)
{
    const short* B = (blockIdx.z == 0) ? B0 : ((blockIdx.z == 1) ? B1 : B2);
    void*        C = (blockIdx.z == 0) ? C0 : ((blockIdx.z == 1) ? C1 : C2);

    __shared__ alignas(16) short sA[128 * 32];
    __shared__ alignas(16) short sB[128 * 32];

    int tid  = threadIdx.x;
    int wave = tid >> 6, lane = tid & 63;
    int lhi  = lane >> 4, llo = lane & 15;
    int wr   = wave >> 1, wc = wave & 1;
    int row0 = blockIdx.x * 128, col0 = blockIdx.y * 128;

    int srow = lane >> 2;          // 0..15: row within 16-row chunk
    int scol = (lane & 3) * 8;     // element offset within row

    f32x4 acc[4][4];
#pragma unroll
    for (int m = 0; m < 4; m++)
#pragma unroll
        for (int n = 0; n < 4; n++)
            acc[m][n] = (f32x4){0.f, 0.f, 0.f, 0.f};

    for (int k0 = 0; k0 < K; k0 += 32) {
        __syncthreads();   // previous iteration's readers done
#pragma unroll
        for (int s2 = 0; s2 < 2; s2++) {
            int rbase = wave * 32 + s2 * 16;   // wave-uniform 16-row chunk
            __builtin_amdgcn_global_load_lds(
                GAS(&A[(size_t)(row0 + rbase + srow) * K + k0 + scol]),
                LAS(&sA[rbase * 32]), 16, 0, 0);
            __builtin_amdgcn_global_load_lds(
                GAS(&B[(size_t)(col0 + rbase + srow) * K + k0 + scol]),
                LAS(&sB[rbase * 32]), 16, 0, 0);
        }
        __syncthreads();   // vmcnt(0) drain + barrier -> tiles visible

        bf16x8 af[4], bfv[4];
#pragma unroll
        for (int m = 0; m < 4; m++)
            af[m] = *(const bf16x8*)&sA[(wr * 64 + m * 16 + llo) * 32 + lhi * 8];
#pragma unroll
        for (int n = 0; n < 4; n++)
            bfv[n] = *(const bf16x8*)&sB[(wc * 64 + n * 16 + llo) * 32 + lhi * 8];
#pragma unroll
        for (int m = 0; m < 4; m++)
#pragma unroll
            for (int n = 0; n < 4; n++)
                acc[m][n] = mfma16(af[m], bfv[n], acc[m][n]);
    }

#pragma unroll
    for (int m = 0; m < 4; m++)
#pragma unroll
        for (int n = 0; n < 4; n++)
#pragma unroll
            for (int r = 0; r < 4; r++) {
                int row = row0 + wr * 64 + m * 16 + lhi * 4 + r;
                int col = col0 + wc * 64 + n * 16 + llo;
                float v = acc[m][n][r];
                if (OBF) ((short*)C)[(size_t)row * N + col] = f2bf(v);
                else     ((float*)C)[(size_t)row * N + col] = v;
            }
}

// ---------- kernel 3: RoPE + RMSNorm, [T][C] bf16 -> per-head [H][T][D] bf16 ----------
__global__ __launch_bounds__(256) void rope_rms(
    const short* __restrict__ Qb, const float* __restrict__ cosT,
    const float* __restrict__ sinT, short* __restrict__ qn, float outscale)
{
    int idx = blockIdx.x * 4 + (threadIdx.x >> 6);   // (t*16 + h)
    int t = idx >> 4, h = idx & 15;
    int d = threadIdx.x & 63;

    float v = bf2f(Qb[t * C_DIM + h * HEAD_DIM + d]);
    int d2 = d & 31;
    float c = cosT[t * 32 + d2], s = sinT[t * 32 + d2];
    float other = __shfl_xor(v, 32);
    float r = (d < 32) ? (v * c + other * s) : (v * c - other * s);

    float sq = r * r;
#pragma unroll
    for (int off = 32; off >= 1; off >>= 1) sq += __shfl_xor(sq, off);
    float inv = rsqrtf(sq * (1.0f / 64.0f) + 1e-6f);

    qn[((size_t)h * T_SEQ + t) * HEAD_DIM + d] = f2bf(r * inv * outscale);
}

// ---------- kernel 4: V transpose [T][C] -> [H][D][T] bf16, scaled ----------
__global__ __launch_bounds__(256) void vtrans(
    const short* __restrict__ Vb, short* __restrict__ vt)
{
    __shared__ short sT[64 * 65];
    int h = blockIdx.y, tb = blockIdx.x;
    int tid = threadIdx.x;
    const float inv64 = 1.0f / (64.0f + 1e-6f);
#pragma unroll
    for (int i = 0; i < 16; i++) {
        int linear = i * 256 + tid;
        int r = linear >> 6, c = linear & 63;
        float v = bf2f(Vb[(size_t)(tb * 64 + r) * C_DIM + h * HEAD_DIM + c]) * inv64;
        sT[c * 65 + r] = f2bf(v);
    }
    __syncthreads();
#pragma unroll
    for (int i = 0; i < 16; i++) {
        int linear = i * 256 + tid;
        int dd = linear >> 6, tt = linear & 63;
        vt[((size_t)(h * HEAD_DIM + dd)) * T_SEQ + tb * 64 + tt] = sT[dd * 65 + tt];
    }
}

// ---------- kernel 5: causal sigmoid attention, zero-LDS P path ----------
// qn,kn: [H][T][D] bf16 (q pre-scaled 1/8). vt: [H][D][T] bf16 (pre-scaled 1/64.000001).
// Grid: 512 blocks = (8 xcd) x (2 heads) x (32 q-tiles, paired so co-resident
// pairs sum to 33 k-tiles). Block: 8 waves = 4 q-bands x 2 kv-teams.
// P never touches LDS: swapped QK^T -> sigmoid in regs -> cvt_pk_bf16 +
// permlane32_swap re-layout -> PV MFMA. LDS only for the final team reduce.
__global__ __launch_bounds__(512, 4) void attn3(
    const short* __restrict__ qn, const short* __restrict__ kn,
    const short* __restrict__ vt, short* __restrict__ yb)
{
    __shared__ alignas(16) float Yred[4 * 32 * 64];   // 32 KiB

    int id  = blockIdx.x;
    int idx = id >> 3;
    int h   = (id & 7) * 2 + (idx & 1);     // 2 heads per XCD for K/V L2 locality
    int sq  = idx >> 1;                      // 0..31
    int t   = (sq < 16) ? (31 - sq) : (sq - 16);   // heavy-first, pair sums uniform

    int tid = threadIdx.x, wave = tid >> 6, lane = tid & 63;
    int lo = lane & 31, hi = lane >> 5;
    int band = wave & 3, team = wave >> 2;

    const short* Qh = qn + (size_t)h * T_SEQ * HEAD_DIM;
    const short* Kh = kn + (size_t)h * T_SEQ * HEAD_DIM;
    const short* Vh = vt + (size_t)h * HEAD_DIM * T_SEQ;

    int q0 = t * 128;
    int qg = q0 + band * 32 + lo;           // this lane's q index (B-col of QK^T)

    const short* Qr = &Qh[(size_t)(q0 + band * 32 + lo) * HEAD_DIM + hi * 8];
    bf16x8 qf0 = *(const bf16x8*)&Qr[0];
    bf16x8 qf1 = *(const bf16x8*)&Qr[16];
    bf16x8 qf2 = *(const bf16x8*)&Qr[32];
    bf16x8 qf3 = *(const bf16x8*)&Qr[48];

    f32x16 yac0, yac1;
#pragma unroll
    for (int r = 0; r < 16; r++) { yac0[r] = 0.f; yac1[r] = 0.f; }

    for (int kt = 0; kt <= t; kt++) {
        int kb = kt * 128 + team * 64;      // this team's 64-kv chunk
        int diag = (kt == t);
#pragma unroll
        for (int f = 0; f < 2; f++) {
            // ---- issue all global loads for this 32-kv chunk up front ----
            const short* Kr = &Kh[(size_t)(kb + f * 32 + lo) * HEAD_DIM + hi * 8];
            bf16x8 kf0 = *(const bf16x8*)&Kr[0];
            bf16x8 kf1 = *(const bf16x8*)&Kr[16];
            bf16x8 kf2 = *(const bf16x8*)&Kr[32];
            bf16x8 kf3 = *(const bf16x8*)&Kr[48];
            const short* Vr = &Vh[(size_t)lo * T_SEQ + kb + f * 32 + hi * 8];
            bf16x8 vf00 = *(const bf16x8*)&Vr[0];                     // d=0, k2=0
            bf16x8 vf01 = *(const bf16x8*)&Vr[16];                    // d=0, k2=1
            bf16x8 vf10 = *(const bf16x8*)&Vr[(size_t)32 * T_SEQ];        // d=1, k2=0
            bf16x8 vf11 = *(const bf16x8*)&Vr[(size_t)32 * T_SEQ + 16];   // d=1, k2=1

            // ---- S^T = K Q^T : col = q (lane&31), row = kv (crow) ----
            f32x16 sv;
#pragma unroll
            for (int r = 0; r < 16; r++) sv[r] = 0.f;
            __builtin_amdgcn_s_setprio(1);
            sv = mfma32(kf0, qf0, sv);
            sv = mfma32(kf1, qf1, sv);
            sv = mfma32(kf2, qf2, sv);
            sv = mfma32(kf3, qf3, sv);
            __builtin_amdgcn_s_setprio(0);

            // ---- sigmoid (+ causal mask on diagonal tile), in place ----
            if (diag) {
#pragma unroll
                for (int r = 0; r < 16; r++) {
                    int kvg = kb + f * 32 + (r & 3) + 8 * (r >> 2) + 4 * hi;
                    float pv = __builtin_amdgcn_rcpf(1.f + __expf(-sv[r]));
                    sv[r] = (kvg <= qg) ? pv : 0.f;
                }
            } else {
#pragma unroll
                for (int r = 0; r < 16; r++)
                    sv[r] = __builtin_amdgcn_rcpf(1.f + __expf(-sv[r]));
            }

            // ---- P re-layout in-register (cvt_pk + permlane32_swap) + PV ----
#pragma unroll
            for (int k2 = 0; k2 < 2; k2++) {
                unsigned wA = cvt_pk_bf16(sv[8 * k2 + 0], sv[8 * k2 + 1]);
                unsigned wC = cvt_pk_bf16(sv[8 * k2 + 2], sv[8 * k2 + 3]);
                unsigned wB = cvt_pk_bf16(sv[8 * k2 + 4], sv[8 * k2 + 5]);
                unsigned wD = cvt_pk_bf16(sv[8 * k2 + 6], sv[8 * k2 + 7]);
                plane_swap(wA, wB);
                plane_swap(wC, wD);
                union { unsigned u[4]; bf16x8 v; } pw;
                pw.u[0] = wA; pw.u[1] = wC; pw.u[2] = wB; pw.u[3] = wD;
                __builtin_amdgcn_s_setprio(1);
                yac0 = mfma32(pw.v, k2 ? vf01 : vf00, yac0);
                yac1 = mfma32(pw.v, k2 ? vf11 : vf10, yac1);
                __builtin_amdgcn_s_setprio(0);
            }
        }
    }

    // ---- cross-team reduce (kv halves) + store ----
    if (team == 1) {
#pragma unroll
        for (int d = 0; d < 2; d++)
#pragma unroll
            for (int r = 0; r < 16; r++) {
                int crow = (r & 3) + 8 * (r >> 2) + 4 * hi;
                Yred[(band * 32 + crow) * 64 + d * 32 + lo] = d ? yac1[r] : yac0[r];
            }
    }
    __syncthreads();
    if (team == 0) {
#pragma unroll
        for (int d = 0; d < 2; d++)
#pragma unroll
            for (int r = 0; r < 16; r++) {
                int crow = (r & 3) + 8 * (r >> 2) + 4 * hi;
                float v = (d ? yac1[r] : yac0[r]) + Yred[(band * 32 + crow) * 64 + d * 32 + lo];
                yb[(size_t)(q0 + band * 32 + crow) * C_DIM + h * HEAD_DIM + d * 32 + lo] = f2bf(v);
            }
    }
}

// ---------- launch ----------
extern "C" void kernel_launch(void* const* d_in, const int* in_sizes, int n_in,
                              void* d_out, int out_size, void* d_ws, size_t ws_size,
                              hipStream_t stream)
{
    const float* x    = (const float*)d_in[0];
    const float* cosT = (const float*)d_in[1];
    const float* sinT = (const float*)d_in[2];
    const float* wq   = (const float*)d_in[3];
    const float* wk   = (const float*)d_in[4];
    const float* wv   = (const float*)d_in[5];
    const float* wp   = (const float*)d_in[6];

    char* ws = (char*)d_ws;
    const size_t MB = 1024 * 1024;
    short* xb  = (short*)(ws + 0);
    short* wqb = (short*)(ws + 8  * MB);
    short* wkb = (short*)(ws + 10 * MB);
    short* wvb = (short*)(ws + 12 * MB);
    short* wpb = (short*)(ws + 14 * MB);
    short* Qb  = (short*)(ws + 16 * MB);
    short* Kb  = (short*)(ws + 24 * MB);
    short* Vb  = (short*)(ws + 32 * MB);
    short* qnb = (short*)(ws + 40 * MB);
    short* knb = (short*)(ws + 48 * MB);
    short* vtb = (short*)(ws + 56 * MB);
    short* yb  = (short*)(ws + 64 * MB);

    cast5<<<dim3(4096, 5, 1), 256, 0, stream>>>(
        x, wq, wk, wv, wp, xb, wqb, wkb, wvb, wpb,
        T_SEQ * C_DIM, C_DIM * C_DIM, C_DIM * C_DIM, C_DIM * C_DIM, C_DIM * C_DIM);

    gemm3<1><<<dim3(32, 8, 3), 256, 0, stream>>>(
        xb, wqb, wkb, wvb, (void*)Qb, (void*)Kb, (void*)Vb, T_SEQ, C_DIM, C_DIM);

    rope_rms<<<16384, 256, 0, stream>>>(Qb, cosT, sinT, qnb, 0.125f);
    rope_rms<<<16384, 256, 0, stream>>>(Kb, cosT, sinT, knb, 1.0f);

    vtrans<<<dim3(64, 16, 1), 256, 0, stream>>>(Vb, vtb);

    attn3<<<512, 512, 0, stream>>>(qnb, knb, vtb, yb);

    gemm3<0><<<dim3(32, 8, 1), 256, 0, stream>>>(
        yb, wpb, wpb, wpb, d_out, d_out, d_out, T_SEQ, C_DIM, C_DIM);
}